// Round 1
// baseline (216.965 us; speedup 1.0000x reference)
//
#include <hip/hip_runtime.h>

// dims from the reference
#define BB 2
#define PP 512
#define NN 8
#define HH 32

typedef float f4     __attribute__((ext_vector_type(4)));
typedef float f32x4  __attribute__((ext_vector_type(4)));
typedef short bf16x8 __attribute__((ext_vector_type(8)));

// float -> bf16 bits, round-nearest-even (inputs are finite, no NaN handling needed)
__device__ __forceinline__ short f2bf(float f) {
  union { float f; unsigned u; } v; v.f = f;
  unsigned r = v.u + 0x7FFFu + ((v.u >> 16) & 1u);
  return (short)(r >> 16);
}

// ---------------------------------------------------------------------------
// Kernel 1: tmpT[b,p1,n,h3,h2] = bf16( sum_h1 d[b,p1,n,h1] * W[n,h1,h2,h3] )
// stored TRANSPOSED (h2 contiguous) so the MFMA B-fragment is a 16B vector load.
// grid: B * N * (P/8) = 1024 blocks; block handles (b, n, 8 consecutive p1).
// ---------------------------------------------------------------------------
__global__ __launch_bounds__(256) void prep_kernel(
    const float* __restrict__ d, const float* __restrict__ W,
    short* __restrict__ tmpT) {
  const int bid    = blockIdx.x;
  const int b      = bid >> 9;
  const int rem    = bid & 511;
  const int n      = rem >> 6;        // 0..7
  const int p1base = (rem & 63) * 8;  // 0..504
  const int t      = threadIdx.x;

  __shared__ float dT[32][8];         // [h1][p1l]
  {
    const int h1 = t & 31, p1l = t >> 5;
    dT[h1][p1l] = d[(size_t)((b * PP + p1base + p1l) * NN + n) * HH + h1];
  }
  __syncthreads();

  const float* Wn = W + (size_t)n * HH * HH * HH;
  #pragma unroll
  for (int pp = 0; pp < 4; ++pp) {
    const int q  = pp * 256 + t;   // 0..1023
    const int h3 = q & 31;
    const int h2 = q >> 5;
    float acc[8] = {0.f, 0.f, 0.f, 0.f, 0.f, 0.f, 0.f, 0.f};
    for (int h1 = 0; h1 < 32; ++h1) {
      const float w = Wn[h1 * 1024 + h2 * 32 + h3];   // coalesced over h3
      const f4 a0 = *(const f4*)&dT[h1][0];           // LDS broadcast
      const f4 a1 = *(const f4*)&dT[h1][4];
      acc[0] = fmaf(a0[0], w, acc[0]);
      acc[1] = fmaf(a0[1], w, acc[1]);
      acc[2] = fmaf(a0[2], w, acc[2]);
      acc[3] = fmaf(a0[3], w, acc[3]);
      acc[4] = fmaf(a1[0], w, acc[4]);
      acc[5] = fmaf(a1[1], w, acc[5]);
      acc[6] = fmaf(a1[2], w, acc[6]);
      acc[7] = fmaf(a1[3], w, acc[7]);
    }
    const size_t obase =
        ((size_t)(b * PP + p1base) * NN + n) * (HH * HH) + h3 * 32 + h2;
    #pragma unroll
    for (int p1l = 0; p1l < 8; ++p1l)
      tmpT[obase + (size_t)p1l * (NN * HH * HH)] = f2bf(acc[p1l]);
  }
}

// ---------------------------------------------------------------------------
// Shared inner GEMM: per wave, 8 p2-tiles x 8 n; one mfma_16x16x32 per 16x16
// C-tile (K = h2 = 32 in a single instruction, C-in = 0).
// A-frag: lane l -> E[m0 + (l&15)][8*(l>>4)+j]  (e fp32, cvt to bf16)
// B-frag: lane l -> T[8*(l>>4)+j][l&15]         (tmpT, h2-contiguous 16B)
// C/D   : col = l&15 (h3), row = (l>>4)*4 + reg (p2)   [verified mapping]
// ---------------------------------------------------------------------------
__device__ __forceinline__ void gemm_pv(const bf16x8 (&bfr)[8][2],
                                        const float* __restrict__ eb,
                                        float* __restrict__ outb,
                                        int wv, int lr, int lk) {
  for (int i = 0; i < 8; ++i) {
    const int m0 = (wv * 8 + i) * 16;   // p2 tile base
    #pragma unroll
    for (int n = 0; n < 8; ++n) {
      const float* ep = eb + (size_t)(((m0 + lr) * NN + n) * HH + lk * 8);
      const f4 e0 = *(const f4*)ep;
      const f4 e1 = *(const f4*)(ep + 4);
      bf16x8 a;
      a[0] = f2bf(e0[0]); a[1] = f2bf(e0[1]); a[2] = f2bf(e0[2]); a[3] = f2bf(e0[3]);
      a[4] = f2bf(e1[0]); a[5] = f2bf(e1[1]); a[6] = f2bf(e1[2]); a[7] = f2bf(e1[3]);
      const f32x4 z = {0.f, 0.f, 0.f, 0.f};
      f32x4 c0 = __builtin_amdgcn_mfma_f32_16x16x32_bf16(a, bfr[n][0], z, 0, 0, 0);
      f32x4 c1 = __builtin_amdgcn_mfma_f32_16x16x32_bf16(a, bfr[n][1], z, 0, 0, 0);
      float* op = outb + (size_t)(m0 + lk * 4) * (NN * HH) + n * HH + lr;
      #pragma unroll
      for (int r = 0; r < 4; ++r) {
        op[(size_t)r * (NN * HH)]      = c0[r];   // h3-tile 0 (cols 0..15)
        op[(size_t)r * (NN * HH) + 16] = c1[r];   // h3-tile 1 (cols 16..31)
      }
    }
  }
}

// ---------------------------------------------------------------------------
// Kernel 2 (ws path): grid = B*P = 1024 blocks, one (b,p1) each. No LDS.
// ---------------------------------------------------------------------------
__global__ __launch_bounds__(256, 4) void vmain_kernel(
    const float* __restrict__ e, const short* __restrict__ tmpT,
    float* __restrict__ out) {
  const int bid = blockIdx.x;
  const int b   = bid >> 9;
  const int p1  = bid & 511;
  const int t   = threadIdx.x;
  const int wv  = t >> 6;
  const int l   = t & 63;
  const int lr  = l & 15;
  const int lk  = l >> 4;

  bf16x8 bfr[8][2];
  const short* tb = tmpT + (size_t)(b * PP + p1) * (NN * HH * HH);
  #pragma unroll
  for (int n = 0; n < 8; ++n)
    #pragma unroll
    for (int c = 0; c < 2; ++c)
      bfr[n][c] = *(const bf16x8*)(tb + n * (HH * HH) + (c * 16 + lr) * 32 + lk * 8);

  gemm_pv(bfr, e + (size_t)b * (PP * NN * HH),
          out + (size_t)(b * PP + p1) * (PP * NN * HH), wv, lr, lk);
}

// ---------------------------------------------------------------------------
// Fallback (no/small ws): compute tmpT into LDS per block, then same GEMM.
// ---------------------------------------------------------------------------
__global__ __launch_bounds__(256, 4) void fused_kernel(
    const float* __restrict__ d, const float* __restrict__ e,
    const float* __restrict__ W, float* __restrict__ out) {
  const int bid = blockIdx.x;
  const int b   = bid >> 9;
  const int p1  = bid & 511;
  const int t   = threadIdx.x;

  __shared__ float dsh[NN * HH];     // d[b,p1,:,:]
  __shared__ short tsh[NN * HH * HH]; // tmpT[n][h3][h2] bf16
  dsh[t] = d[(size_t)(b * PP + p1) * (NN * HH) + t];
  __syncthreads();

  const int h3  = t & 31;
  const int h2b = t >> 5;            // 0..7
  for (int n = 0; n < 8; ++n) {
    f4 dv[8];
    #pragma unroll
    for (int j = 0; j < 8; ++j) dv[j] = *(const f4*)&dsh[n * 32 + j * 4];
    const float* Wn = W + (size_t)n * (HH * HH * HH);
    #pragma unroll
    for (int h2s = 0; h2s < 4; ++h2s) {
      const int h2 = h2s * 8 + h2b;
      float acc = 0.f;
      #pragma unroll
      for (int j = 0; j < 8; ++j)
        #pragma unroll
        for (int k = 0; k < 4; ++k)
          acc = fmaf(dv[j][k], Wn[(j * 4 + k) * 1024 + h2 * 32 + h3], acc);
      tsh[n * 1024 + h3 * 32 + h2] = f2bf(acc);
    }
  }
  __syncthreads();

  const int wv = t >> 6;
  const int l  = t & 63;
  const int lr = l & 15;
  const int lk = l >> 4;
  bf16x8 bfr[8][2];
  #pragma unroll
  for (int n = 0; n < 8; ++n)
    #pragma unroll
    for (int c = 0; c < 2; ++c)
      bfr[n][c] = *(const bf16x8*)&tsh[n * (HH * HH) + (c * 16 + lr) * 32 + lk * 8];

  gemm_pv(bfr, e + (size_t)b * (PP * NN * HH),
          out + (size_t)(b * PP + p1) * (PP * NN * HH), wv, lr, lk);
}

extern "C" void kernel_launch(void* const* d_in, const int* in_sizes, int n_in,
                              void* d_out, int out_size, void* d_ws, size_t ws_size,
                              hipStream_t stream) {
  const float* d = (const float*)d_in[0];
  const float* e = (const float*)d_in[1];
  const float* W = (const float*)d_in[2];
  float* out = (float*)d_out;

  const size_t tmp_bytes = (size_t)BB * PP * NN * HH * HH * sizeof(short); // 16.8 MB
  if (ws_size >= tmp_bytes) {
    short* tmpT = (short*)d_ws;
    prep_kernel<<<dim3(BB * NN * (PP / 8)), dim3(256), 0, stream>>>(d, W, tmpT);
    vmain_kernel<<<dim3(BB * PP), dim3(256), 0, stream>>>(e, tmpT, out);
  } else {
    fused_kernel<<<dim3(BB * PP), dim3(256), 0, stream>>>(d, e, W, out);
  }
}

// Round 2
// 151.298 us; speedup vs baseline: 1.4340x; 1.4340x over previous
//
#include <hip/hip_runtime.h>

// dims from the reference
#define BB 2
#define PP 512
#define NN 8
#define HH 32

typedef float f4     __attribute__((ext_vector_type(4)));
typedef float f32x4  __attribute__((ext_vector_type(4)));
typedef short bf16x8 __attribute__((ext_vector_type(8)));

// float -> bf16 bits, round-nearest-even
__device__ __forceinline__ short f2bf(float f) {
  union { float f; unsigned u; } v; v.f = f;
  unsigned r = v.u + 0x7FFFu + ((v.u >> 16) & 1u);
  return (short)(r >> 16);
}

// ---------------------------------------------------------------------------
// Kernel 1: tmpT[b,p1,n,h3,h2] = bf16( sum_h1 d[b,p1,n,h1] * W[n,h1,h2,h3] )
// stored TRANSPOSED (h2 contiguous) -> MFMA fragment is a contiguous 16B load.
// ---------------------------------------------------------------------------
__global__ __launch_bounds__(256) void prep_kernel(
    const float* __restrict__ d, const float* __restrict__ W,
    short* __restrict__ tmpT) {
  const int bid    = blockIdx.x;
  const int b      = bid >> 9;
  const int rem    = bid & 511;
  const int n      = rem >> 6;        // 0..7
  const int p1base = (rem & 63) * 8;  // 0..504
  const int t      = threadIdx.x;

  __shared__ float dT[32][8];         // [h1][p1l]
  {
    const int h1 = t & 31, p1l = t >> 5;
    dT[h1][p1l] = d[(size_t)((b * PP + p1base + p1l) * NN + n) * HH + h1];
  }
  __syncthreads();

  const float* Wn = W + (size_t)n * HH * HH * HH;
  #pragma unroll
  for (int pp = 0; pp < 4; ++pp) {
    const int q  = pp * 256 + t;   // 0..1023
    const int h3 = q & 31;
    const int h2 = q >> 5;
    float acc[8] = {0.f, 0.f, 0.f, 0.f, 0.f, 0.f, 0.f, 0.f};
    for (int h1 = 0; h1 < 32; ++h1) {
      const float w = Wn[h1 * 1024 + h2 * 32 + h3];   // coalesced over h3
      const f4 a0 = *(const f4*)&dT[h1][0];
      const f4 a1 = *(const f4*)&dT[h1][4];
      acc[0] = fmaf(a0[0], w, acc[0]);
      acc[1] = fmaf(a0[1], w, acc[1]);
      acc[2] = fmaf(a0[2], w, acc[2]);
      acc[3] = fmaf(a0[3], w, acc[3]);
      acc[4] = fmaf(a1[0], w, acc[4]);
      acc[5] = fmaf(a1[1], w, acc[5]);
      acc[6] = fmaf(a1[2], w, acc[6]);
      acc[7] = fmaf(a1[3], w, acc[7]);
    }
    const size_t obase =
        ((size_t)(b * PP + p1base) * NN + n) * (HH * HH) + h3 * 32 + h2;
    #pragma unroll
    for (int p1l = 0; p1l < 8; ++p1l)
      tmpT[obase + (size_t)p1l * (NN * HH * HH)] = f2bf(acc[p1l]);
  }
}

// ---------------------------------------------------------------------------
// Kernel 1b: eB[b,p2,n,h2] = bf16(e[b,p2,n,h2]). 1M floats -> 512 KB bf16.
// ---------------------------------------------------------------------------
__global__ __launch_bounds__(256) void ecvt_kernel(
    const float* __restrict__ e, short* __restrict__ eB) {
  const int i = (blockIdx.x * 256 + threadIdx.x) * 8;  // grid covers B*P*N*H/8
  const f4 e0 = *(const f4*)(e + i);
  const f4 e1 = *(const f4*)(e + i + 4);
  bf16x8 v;
  v[0] = f2bf(e0[0]); v[1] = f2bf(e0[1]); v[2] = f2bf(e0[2]); v[3] = f2bf(e0[3]);
  v[4] = f2bf(e1[0]); v[5] = f2bf(e1[1]); v[6] = f2bf(e1[2]); v[7] = f2bf(e1[3]);
  *(bf16x8*)(eB + i) = v;
}

// ---------------------------------------------------------------------------
// Kernel 2: D = T^T * E^T per (b,p1,n).  Swapped operands vs round-0:
//   A-frag = tmpT rows (h3), B-frag = e rows (p2) -> loads are identical,
//   but C/D now has col = p2 (lane&15), rows = 4 CONSECUTIVE h3 per lane
//   ((lane>>4)*4 + reg) -> dwordx4 stores, lk groups fill 64B, c0/c1 fill
//   the 128B line.  grid = B*P = 1024 blocks, 4 waves, no LDS.
// ---------------------------------------------------------------------------
__global__ __launch_bounds__(256, 4) void vmain_kernel(
    const short* __restrict__ eB, const short* __restrict__ tmpT,
    float* __restrict__ out) {
  const int bid = blockIdx.x;
  const int b   = bid >> 9;
  const int p1  = bid & 511;
  const int t   = threadIdx.x;
  const int wv  = t >> 6;
  const int l   = t & 63;
  const int lr  = l & 15;
  const int lk  = l >> 4;

  // A-fragments: T^T rows h3 = c*16 + lr, k = h2 = 8*lk + j (contiguous 16B)
  bf16x8 bfr[8][2];
  const short* tb = tmpT + (size_t)(b * PP + p1) * (NN * HH * HH);
  #pragma unroll
  for (int n = 0; n < 8; ++n)
    #pragma unroll
    for (int c = 0; c < 2; ++c)
      bfr[n][c] = *(const bf16x8*)(tb + n * (HH * HH) + (c * 16 + lr) * 32 + lk * 8);

  const short* ebb  = eB + (size_t)b * (PP * NN * HH);
  float*       outb = out + (size_t)(b * PP + p1) * (PP * NN * HH);
  const f32x4  z    = {0.f, 0.f, 0.f, 0.f};

  for (int i = 0; i < 8; ++i) {
    const int m0 = (wv * 8 + i) * 16;   // p2 tile base
    #pragma unroll
    for (int n = 0; n < 8; ++n) {
      // B-frag: E^T col p2 = m0+lr, k = h2 = 8*lk + j (contiguous 16B bf16)
      const bf16x8 a =
          *(const bf16x8*)(ebb + (size_t)((m0 + lr) * NN + n) * HH + lk * 8);
      const f32x4 c0 = __builtin_amdgcn_mfma_f32_16x16x32_bf16(bfr[n][0], a, z, 0, 0, 0);
      const f32x4 c1 = __builtin_amdgcn_mfma_f32_16x16x32_bf16(bfr[n][1], a, z, 0, 0, 0);
      // lane holds out[b,p1, p2=m0+lr, n, h3 = c*16 + 4*lk + (0..3)]
      float* op = outb + (size_t)(m0 + lr) * (NN * HH) + n * HH + lk * 4;
      *(f32x4*)op        = c0;
      *(f32x4*)(op + 16) = c1;
    }
  }
}

// ---------------------------------------------------------------------------
// Fallback (no/small ws): round-0 fused kernel (correct, slower).
// ---------------------------------------------------------------------------
__device__ __forceinline__ void gemm_pv_f32e(const bf16x8 (&bfr)[8][2],
                                             const float* __restrict__ eb,
                                             float* __restrict__ outb,
                                             int wv, int lr, int lk) {
  for (int i = 0; i < 8; ++i) {
    const int m0 = (wv * 8 + i) * 16;
    #pragma unroll
    for (int n = 0; n < 8; ++n) {
      const float* ep = eb + (size_t)(((m0 + lr) * NN + n) * HH + lk * 8);
      const f4 e0 = *(const f4*)ep;
      const f4 e1 = *(const f4*)(ep + 4);
      bf16x8 a;
      a[0] = f2bf(e0[0]); a[1] = f2bf(e0[1]); a[2] = f2bf(e0[2]); a[3] = f2bf(e0[3]);
      a[4] = f2bf(e1[0]); a[5] = f2bf(e1[1]); a[6] = f2bf(e1[2]); a[7] = f2bf(e1[3]);
      const f32x4 z = {0.f, 0.f, 0.f, 0.f};
      const f32x4 c0 = __builtin_amdgcn_mfma_f32_16x16x32_bf16(bfr[n][0], a, z, 0, 0, 0);
      const f32x4 c1 = __builtin_amdgcn_mfma_f32_16x16x32_bf16(bfr[n][1], a, z, 0, 0, 0);
      float* op = outb + (size_t)(m0 + lr) * (NN * HH) + n * HH + lk * 4;
      *(f32x4*)op        = c0;
      *(f32x4*)(op + 16) = c1;
    }
  }
}

__global__ __launch_bounds__(256, 4) void fused_kernel(
    const float* __restrict__ d, const float* __restrict__ e,
    const float* __restrict__ W, float* __restrict__ out) {
  const int bid = blockIdx.x;
  const int b   = bid >> 9;
  const int p1  = bid & 511;
  const int t   = threadIdx.x;

  __shared__ float dsh[NN * HH];
  __shared__ short tsh[NN * HH * HH];
  dsh[t] = d[(size_t)(b * PP + p1) * (NN * HH) + t];
  __syncthreads();

  const int h3  = t & 31;
  const int h2b = t >> 5;
  for (int n = 0; n < 8; ++n) {
    f4 dv[8];
    #pragma unroll
    for (int j = 0; j < 8; ++j) dv[j] = *(const f4*)&dsh[n * 32 + j * 4];
    const float* Wn = W + (size_t)n * (HH * HH * HH);
    #pragma unroll
    for (int h2s = 0; h2s < 4; ++h2s) {
      const int h2 = h2s * 8 + h2b;
      float acc = 0.f;
      #pragma unroll
      for (int j = 0; j < 8; ++j)
        #pragma unroll
        for (int k = 0; k < 4; ++k)
          acc = fmaf(dv[j][k], Wn[(j * 4 + k) * 1024 + h2 * 32 + h3], acc);
      tsh[n * 1024 + h3 * 32 + h2] = f2bf(acc);
    }
  }
  __syncthreads();

  const int wv = t >> 6;
  const int l  = t & 63;
  const int lr = l & 15;
  const int lk = l >> 4;
  bf16x8 bfr[8][2];
  #pragma unroll
  for (int n = 0; n < 8; ++n)
    #pragma unroll
    for (int c = 0; c < 2; ++c)
      bfr[n][c] = *(const bf16x8*)&tsh[n * (HH * HH) + (c * 16 + lr) * 32 + lk * 8];

  gemm_pv_f32e(bfr, e + (size_t)b * (PP * NN * HH),
               out + (size_t)(b * PP + p1) * (PP * NN * HH), wv, lr, lk);
}

extern "C" void kernel_launch(void* const* d_in, const int* in_sizes, int n_in,
                              void* d_out, int out_size, void* d_ws, size_t ws_size,
                              hipStream_t stream) {
  const float* d = (const float*)d_in[0];
  const float* e = (const float*)d_in[1];
  const float* W = (const float*)d_in[2];
  float* out = (float*)d_out;

  const size_t tmp_bytes = (size_t)BB * PP * NN * HH * HH * sizeof(short); // 16.78 MB
  const size_t eb_bytes  = (size_t)BB * PP * NN * HH * sizeof(short);      // 512 KB
  if (ws_size >= tmp_bytes + eb_bytes) {
    short* tmpT = (short*)d_ws;
    short* eB   = (short*)((char*)d_ws + tmp_bytes);
    prep_kernel<<<dim3(BB * NN * (PP / 8)), dim3(256), 0, stream>>>(d, W, tmpT);
    ecvt_kernel<<<dim3(BB * PP * NN * HH / (256 * 8)), dim3(256), 0, stream>>>(e, eB);
    vmain_kernel<<<dim3(BB * PP), dim3(256), 0, stream>>>(eB, tmpT, out);
  } else {
    fused_kernel<<<dim3(BB * PP), dim3(256), 0, stream>>>(d, e, W, out);
  }
}

// Round 3
// 131.206 us; speedup vs baseline: 1.6536x; 1.1531x over previous
//
#include <hip/hip_runtime.h>

// dims from the reference
#define BB 2
#define PP 512
#define NN 8
#define HH 32

typedef float f4     __attribute__((ext_vector_type(4)));
typedef float f32x4  __attribute__((ext_vector_type(4)));
typedef short bf16x8 __attribute__((ext_vector_type(8)));

// float -> bf16 bits, round-nearest-even
__device__ __forceinline__ short f2bf(float f) {
  union { float f; unsigned u; } v; v.f = f;
  unsigned r = v.u + 0x7FFFu + ((v.u >> 16) & 1u);
  return (short)(r >> 16);
}

// ---------------------------------------------------------------------------
// Kernel 0: WT[n][h1][h3][h2] = W[n][h1][h2][h3]  (32x32 LDS transpose/tile)
// grid = N*H = 256 blocks. W is 1 MB -> L2-resident afterwards.
// ---------------------------------------------------------------------------
__global__ __launch_bounds__(256) void wtrans_kernel(
    const float* __restrict__ W, float* __restrict__ WT) {
  const int blk = blockIdx.x;          // n*32 + h1
  const int t   = threadIdx.x;
  __shared__ float ls[32][33];         // +1 pad: conflict-free both ways
  const float* src = W  + (size_t)blk * 1024;
  float*       dst = WT + (size_t)blk * 1024;
  #pragma unroll
  for (int r = 0; r < 4; ++r) {
    const int h2 = r * 8 + (t >> 5), h3 = t & 31;
    ls[h2][h3] = src[h2 * 32 + h3];    // coalesced
  }
  __syncthreads();
  #pragma unroll
  for (int r = 0; r < 4; ++r) {
    const int h3 = r * 8 + (t >> 5), h2 = t & 31;
    dst[h3 * 32 + h2] = ls[h2][h3];    // coalesced
  }
}

// ---------------------------------------------------------------------------
// Kernel 1: prep2 — tmpT[b,p1,n,h3,h2] = bf16( sum_h1 d * WT )
// Block = (b, n-pair, 8 p1). Thread = (n', h3, h2-group-of-8).
// Vector WT loads (h2-contiguous), bf16x8 (16B) stores -> 1KB dense per wave.
// ---------------------------------------------------------------------------
__global__ __launch_bounds__(256) void prep2_kernel(
    const float* __restrict__ d, const float* __restrict__ WT,
    short* __restrict__ tmpT) {
  const int bid    = blockIdx.x;       // 0..511
  const int b      = bid >> 8;
  const int rem    = bid & 255;
  const int npair  = rem >> 6;         // 0..3
  const int p1base = (rem & 63) * 8;
  const int t      = threadIdx.x;

  __shared__ float dsh[2][32][8];      // [n'][h1][p1l]
  {
    const int h1 = t & 31, p1l = (t >> 5) & 7;
    #pragma unroll
    for (int r = 0; r < 2; ++r)
      dsh[r][h1][p1l] =
          d[(size_t)((b * PP + p1base + p1l) * NN + npair * 2 + r) * HH + h1];
  }
  __syncthreads();

  const int np  = t >> 7;              // 0/1
  const int h3  = (t >> 2) & 31;
  const int h2g = t & 3;               // h2 base = h2g*8
  const int n   = npair * 2 + np;

  float acc[8][8];                     // [p1l][h2loc]
  #pragma unroll
  for (int p = 0; p < 8; ++p)
    #pragma unroll
    for (int q = 0; q < 8; ++q) acc[p][q] = 0.f;

  const float* wb = WT + ((size_t)(n * HH) * HH + h3) * HH + h2g * 8;
  for (int h1 = 0; h1 < 32; ++h1) {
    const f4 w0 = *(const f4*)(wb + (size_t)h1 * 1024);
    const f4 w1 = *(const f4*)(wb + (size_t)h1 * 1024 + 4);
    const f4 d0 = *(const f4*)&dsh[np][h1][0];   // LDS broadcast
    const f4 d1 = *(const f4*)&dsh[np][h1][4];
    #pragma unroll
    for (int p = 0; p < 4; ++p) {
      #pragma unroll
      for (int q = 0; q < 4; ++q) {
        acc[p][q]         = fmaf(d0[p], w0[q], acc[p][q]);
        acc[p][q + 4]     = fmaf(d0[p], w1[q], acc[p][q + 4]);
        acc[p + 4][q]     = fmaf(d1[p], w0[q], acc[p + 4][q]);
        acc[p + 4][q + 4] = fmaf(d1[p], w1[q], acc[p + 4][q + 4]);
      }
    }
  }

  const size_t obase =
      ((size_t)(b * PP + p1base) * NN + n) * (HH * HH) + h3 * 32 + h2g * 8;
  #pragma unroll
  for (int p = 0; p < 8; ++p) {
    bf16x8 v;
    #pragma unroll
    for (int q = 0; q < 8; ++q) v[q] = f2bf(acc[p][q]);
    *(bf16x8*)(tmpT + obase + (size_t)p * (NN * HH * HH)) = v;
  }
}

// ---------------------------------------------------------------------------
// Kernel 1b: eB = bf16(e)
// ---------------------------------------------------------------------------
__global__ __launch_bounds__(256) void ecvt_kernel(
    const float* __restrict__ e, short* __restrict__ eB) {
  const int i = (blockIdx.x * 256 + threadIdx.x) * 8;
  const f4 e0 = *(const f4*)(e + i);
  const f4 e1 = *(const f4*)(e + i + 4);
  bf16x8 v;
  v[0] = f2bf(e0[0]); v[1] = f2bf(e0[1]); v[2] = f2bf(e0[2]); v[3] = f2bf(e0[3]);
  v[4] = f2bf(e1[0]); v[5] = f2bf(e1[1]); v[6] = f2bf(e1[2]); v[7] = f2bf(e1[3]);
  *(bf16x8*)(eB + i) = v;
}

// ---------------------------------------------------------------------------
// Kernel 2: vmain v3 — MFMA + per-wave LDS-transpose epilogue.
// Per (i, n-half): 8 MFMA frags -> swizzled ds_write_b128 into private 8KB
// buffer -> row-linear ds_read_b128 -> 1KB-DENSE global_store_dwordx4
// (2 x 512B segments/instr instead of 16 x 64B). No __syncthreads.
// ---------------------------------------------------------------------------
__global__ __launch_bounds__(256, 4) void vmain_kernel(
    const short* __restrict__ eB, const short* __restrict__ tmpT,
    float* __restrict__ out) {
  const int bid = blockIdx.x;
  const int b   = bid >> 9;
  const int p1  = bid & 511;
  const int t   = threadIdx.x;
  const int wv  = t >> 6;
  const int l   = t & 63;
  const int lr  = l & 15;
  const int lk  = l >> 4;

  __shared__ float lbuf[4][16][128];   // 32 KB: per-wave [p2row][4n x 32h3]
  float* wl = &lbuf[wv][0][0];

  // A-fragments: T^T rows h3 = c*16 + lr, k = h2 = 8*lk + j (contiguous 16B)
  bf16x8 bfr[8][2];
  const short* tb = tmpT + (size_t)(b * PP + p1) * (NN * HH * HH);
  #pragma unroll
  for (int n = 0; n < 8; ++n)
    #pragma unroll
    for (int c = 0; c < 2; ++c)
      bfr[n][c] = *(const bf16x8*)(tb + n * (HH * HH) + (c * 16 + lr) * 32 + lk * 8);

  const short* ebb  = eB + (size_t)b * (PP * NN * HH);
  float*       outb = out + (size_t)(b * PP + p1) * (PP * NN * HH);
  const f32x4  z    = {0.f, 0.f, 0.f, 0.f};

  for (int i = 0; i < 8; ++i) {
    const int m0 = (wv * 8 + i) * 16;  // p2 tile base
    #pragma unroll
    for (int half = 0; half < 2; ++half) {
      const int n0 = half * 4;
      // compute + swizzled LDS write (slot s XOR lr&7: bank-balanced)
      #pragma unroll
      for (int nn = 0; nn < 4; ++nn) {
        const int n = n0 + nn;
        const bf16x8 a =
            *(const bf16x8*)(ebb + (size_t)((m0 + lr) * NN + n) * HH + lk * 8);
        const f32x4 c0 = __builtin_amdgcn_mfma_f32_16x16x32_bf16(bfr[n][0], a, z, 0, 0, 0);
        const f32x4 c1 = __builtin_amdgcn_mfma_f32_16x16x32_bf16(bfr[n][1], a, z, 0, 0, 0);
        const int s0 = (nn * 8 + lk)     ^ (lr & 7);
        const int s1 = (nn * 8 + 4 + lk) ^ (lr & 7);
        *(f32x4*)(wl + lr * 128 + s0 * 4) = c0;
        *(f32x4*)(wl + lr * 128 + s1 * 4) = c1;
      }
      // row-linear read + dense store: instr j covers rows 2j,2j+1 (1KB)
      #pragma unroll
      for (int j = 0; j < 8; ++j) {
        const int row  = 2 * j + (l >> 5);
        const int slot = l & 31;
        const f32x4 v = *(const f32x4*)(wl + row * 128 + ((slot ^ (row & 7)) * 4));
        *(f32x4*)(outb + (size_t)(m0 + row) * (NN * HH) + n0 * HH + slot * 4) = v;
      }
    }
  }
}

// ---------------------------------------------------------------------------
// Fallback (no/small ws): fused kernel (correct, slower).
// ---------------------------------------------------------------------------
__global__ __launch_bounds__(256, 4) void fused_kernel(
    const float* __restrict__ d, const float* __restrict__ e,
    const float* __restrict__ W, float* __restrict__ out) {
  const int bid = blockIdx.x;
  const int b   = bid >> 9;
  const int p1  = bid & 511;
  const int t   = threadIdx.x;

  __shared__ float dsh[NN * HH];
  __shared__ short tsh[NN * HH * HH];
  dsh[t] = d[(size_t)(b * PP + p1) * (NN * HH) + t];
  __syncthreads();

  const int h3  = t & 31;
  const int h2b = t >> 5;
  for (int n = 0; n < 8; ++n) {
    f4 dv[8];
    #pragma unroll
    for (int j = 0; j < 8; ++j) dv[j] = *(const f4*)&dsh[n * 32 + j * 4];
    const float* Wn = W + (size_t)n * (HH * HH * HH);
    #pragma unroll
    for (int h2s = 0; h2s < 4; ++h2s) {
      const int h2 = h2s * 8 + h2b;
      float acc = 0.f;
      #pragma unroll
      for (int j = 0; j < 8; ++j)
        #pragma unroll
        for (int k = 0; k < 4; ++k)
          acc = fmaf(dv[j][k], Wn[(j * 4 + k) * 1024 + h2 * 32 + h3], acc);
      tsh[n * 1024 + h3 * 32 + h2] = f2bf(acc);
    }
  }
  __syncthreads();

  const int wv = t >> 6;
  const int l  = t & 63;
  const int lr = l & 15;
  const int lk = l >> 4;
  bf16x8 bfr[8][2];
  #pragma unroll
  for (int n = 0; n < 8; ++n)
    #pragma unroll
    for (int c = 0; c < 2; ++c)
      bfr[n][c] = *(const bf16x8*)&tsh[n * (HH * HH) + (c * 16 + lr) * 32 + lk * 8];

  const float* eb   = e + (size_t)b * (PP * NN * HH);
  float*       outb = out + (size_t)(b * PP + p1) * (PP * NN * HH);
  const f32x4  z    = {0.f, 0.f, 0.f, 0.f};
  for (int i = 0; i < 8; ++i) {
    const int m0 = (wv * 8 + i) * 16;
    #pragma unroll
    for (int n = 0; n < 8; ++n) {
      const float* ep = eb + (size_t)(((m0 + lr) * NN + n) * HH + lk * 8);
      const f4 e0 = *(const f4*)ep;
      const f4 e1 = *(const f4*)(ep + 4);
      bf16x8 a;
      a[0] = f2bf(e0[0]); a[1] = f2bf(e0[1]); a[2] = f2bf(e0[2]); a[3] = f2bf(e0[3]);
      a[4] = f2bf(e1[0]); a[5] = f2bf(e1[1]); a[6] = f2bf(e1[2]); a[7] = f2bf(e1[3]);
      const f32x4 c0 = __builtin_amdgcn_mfma_f32_16x16x32_bf16(bfr[n][0], a, z, 0, 0, 0);
      const f32x4 c1 = __builtin_amdgcn_mfma_f32_16x16x32_bf16(bfr[n][1], a, z, 0, 0, 0);
      float* op = outb + (size_t)(m0 + lr) * (NN * HH) + n * HH + lk * 4;
      *(f32x4*)op        = c0;
      *(f32x4*)(op + 16) = c1;
    }
  }
}

extern "C" void kernel_launch(void* const* d_in, const int* in_sizes, int n_in,
                              void* d_out, int out_size, void* d_ws, size_t ws_size,
                              hipStream_t stream) {
  const float* d = (const float*)d_in[0];
  const float* e = (const float*)d_in[1];
  const float* W = (const float*)d_in[2];
  float* out = (float*)d_out;

  const size_t tmp_bytes = (size_t)BB * PP * NN * HH * HH * sizeof(short); // 16.78 MB
  const size_t eb_bytes  = (size_t)BB * PP * NN * HH * sizeof(short);      // 512 KB
  const size_t wt_bytes  = (size_t)NN * HH * HH * HH * sizeof(float);      // 1 MB
  if (ws_size >= tmp_bytes + eb_bytes + wt_bytes) {
    short* tmpT = (short*)d_ws;
    short* eB   = (short*)((char*)d_ws + tmp_bytes);
    float* WT   = (float*)((char*)d_ws + tmp_bytes + eb_bytes);
    wtrans_kernel<<<dim3(NN * HH), dim3(256), 0, stream>>>(W, WT);
    ecvt_kernel<<<dim3(BB * PP * NN * HH / (256 * 8)), dim3(256), 0, stream>>>(e, eB);
    prep2_kernel<<<dim3(BB * 4 * (PP / 8)), dim3(256), 0, stream>>>(d, WT, tmpT);
    vmain_kernel<<<dim3(BB * PP), dim3(256), 0, stream>>>(eB, tmpT, out);
  } else {
    fused_kernel<<<dim3(BB * PP), dim3(256), 0, stream>>>(d, e, W, out);
  }
}